// Round 5
// baseline (173.720 us; speedup 1.0000x reference)
//
#include <hip/hip_runtime.h>
#include <float.h>

// Quantize: z [8,4096,512] f32, embed_w [512,128] f32, GROUPS=4
// flat = z.reshape(131072,128); dist to 512 codes; argmin; gather; MSE scalar.
// d_out (f32): z_q_st [16777216], diff [1], ind [131072] (as float).
//
// fp16 2-term split MFMA: dot = xh*(wh + wl), xh = fp16(x), w = wh + wl.
// Score error <~8e-3 << TAU_A=0.02; every row with top-2 margin < TAU_A is
// re-solved exactly in fp64 => exact argmin indices.
// W preconverted+preswizzled once; double-buffered 32-code chunks via
// global_load_lds; 64 rows/wave (2-wave blocks) to halve LDS read traffic.

typedef _Float16 half8 __attribute__((ext_vector_type(8)));
typedef __attribute__((ext_vector_type(4))) float f32x4;

constexpr int Dn = 128;
constexpr int K  = 512;
constexpr long long Mrows = 131072;
constexpr int RPW  = 64;                     // rows per wave
constexpr int WAVES = 2;                     // waves per block
constexpr int RPB  = RPW * WAVES;            // 128 rows per block
constexpr int NBLK = (int)(Mrows / RPB);     // 1024
constexpr int CHUNK = 32;                    // codes per LDS chunk
constexpr int NCH   = K / CHUNK;             // 16
constexpr float TAU_A = 0.02f;               // score-margin for fp64 re-solve

constexpr size_t ZQ_SIZE  = (size_t)Mrows * Dn;
constexpr size_t DIFF_OFF = ZQ_SIZE;
constexpr size_t IND_OFF  = ZQ_SIZE + 1;

__device__ inline void gload_lds16(const void* g, void* l) {
    __builtin_amdgcn_global_load_lds(
        (const __attribute__((address_space(1))) unsigned int*)g,
        (__attribute__((address_space(3))) unsigned int*)l,
        16, 0, 0);
}

__global__ void wnorm_kernel(const float* __restrict__ W, float* __restrict__ wn2) {
    int k = blockIdx.x * blockDim.x + threadIdx.x;
    if (k < K) {
        double s = 0.0;
        const float* w = W + (size_t)k * Dn;
        #pragma unroll 4
        for (int i = 0; i < Dn; ++i) { double v = (double)w[i]; s += v * v; }
        wn2[k] = (float)(-0.5 * s);
    }
}

// W -> fp16 hi/lo, pre-swizzled granule order.
// Per chunk ch (32 codes): 16 KB = [hi 8KB][lo 8KB].
// Hi-region granule index G = code_l*16 + gs holds physical granule
// g = gs ^ (code_l & 7) of that code's row (8 halfs per 16B granule).
__global__ void prep_kernel(const float* __restrict__ W, unsigned short* __restrict__ Wp) {
    int t = blockIdx.x * 256 + threadIdx.x;  // 0..8191 (512 codes * 16 granules)
    int code   = t >> 4;
    int gs     = t & 15;
    int ch     = code >> 5;
    int code_l = code & 31;
    int g      = gs ^ (code_l & 7);
    const float* src = W + (size_t)code * Dn + g * 8;
    ushort4 h[2], l[2];
    #pragma unroll
    for (int half = 0; half < 2; ++half) {
        float4 v = *(const float4*)(src + half * 4);
        float vv[4] = {v.x, v.y, v.z, v.w};
        unsigned short* hp = (unsigned short*)&h[half];
        unsigned short* lp = (unsigned short*)&l[half];
        #pragma unroll
        for (int e = 0; e < 4; ++e) {
            _Float16 hh = (_Float16)vv[e];
            _Float16 ll = (_Float16)(vv[e] - (float)hh);
            hp[e] = __builtin_bit_cast(unsigned short, hh);
            lp[e] = __builtin_bit_cast(unsigned short, ll);
        }
    }
    size_t base = (size_t)ch * 8192 + (size_t)(code_l * 16 + gs) * 8;   // ushort units
    *(ushort4*)(Wp + base)            = h[0];
    *(ushort4*)(Wp + base + 4)        = h[1];
    *(ushort4*)(Wp + base + 4096)     = l[0];
    *(ushort4*)(Wp + base + 4096 + 4) = l[1];
}

__global__ __launch_bounds__(128) void vq_main(
        const float* __restrict__ Z, const float* __restrict__ W,
        const unsigned short* __restrict__ Wp, const float* __restrict__ wn2,
        float* __restrict__ out, double* __restrict__ diffsum) {
    __shared__ __align__(16) char Wbuf[2][16384];   // double-buffered 32-code chunk
    __shared__ float wn2_s[K];
    __shared__ int   sIdx[RPB];
    __shared__ int   sFlag[RPB];
    __shared__ float xn_s[RPB];
    __shared__ float wpart[WAVES];

    const int tid  = threadIdx.x;
    const int w    = tid >> 6;
    const int lane = tid & 63;
    const int lm   = lane & 15;        // A row / B col within 16-tile
    const int lg   = lane >> 4;        // k-block (0..3)
    const size_t row0 = (size_t)blockIdx.x * RPB;

    // ---- staging: pure DMA (layout pre-swizzled in Wp) ----
    auto stage = [&](int bi, int ch) {
        const char* gsrc = (const char*)Wp + (size_t)ch * 16384;
        char* lb = &Wbuf[bi][0];
        #pragma unroll
        for (int it = 0; it < 8; ++it) {
            const int gb = (w * 8 + it) * 64;            // wave-uniform granule base
            gload_lds16(gsrc + (size_t)(gb + lane) * 16, lb + (size_t)gb * 16);
        }
    };
    stage(0, 0);                        // issue chunk 0 DMA first

    // ---- X fragments (fp16) + exact row norms, in registers ----
    // A-frag (16x16x32): lane lm = row, k = lg*8 + j within k-step ks
    half8 ah[4][4];                     // [r 16-row tile][ks]
    #pragma unroll
    for (int r = 0; r < 4; ++r) {
        const size_t grow = row0 + (size_t)w * RPW + r * 16 + lm;
        float s2 = 0.f;
        #pragma unroll
        for (int ks = 0; ks < 4; ++ks) {
            const float* xp = Z + grow * Dn + ks * 32 + lg * 8;
            float4 x0 = *(const float4*)xp;
            float4 x1 = *(const float4*)(xp + 4);
            float xv[8] = {x0.x, x0.y, x0.z, x0.w, x1.x, x1.y, x1.z, x1.w};
            #pragma unroll
            for (int j = 0; j < 8; ++j) {
                ah[r][ks][j] = (_Float16)xv[j];
                s2 += xv[j] * xv[j];
            }
        }
        s2 += __shfl_xor(s2, 16);
        s2 += __shfl_xor(s2, 32);      // reduce across lg -> full ||x||^2
        if (lg == 0) xn_s[w * RPW + r * 16 + lm] = s2;
    }
    // wn2 -> LDS (broadcast table)
    #pragma unroll
    for (int i = 0; i < K / 128; ++i) wn2_s[tid + i * 128] = wn2[tid + i * 128];

    // max-tracking of a = dot - 0.5*||w||^2  (argmin dist == argmax a)
    float m1[4][4], m2[4][4];
    int   i1[4][4];
    #pragma unroll
    for (int r = 0; r < 4; ++r)
        #pragma unroll
        for (int j = 0; j < 4; ++j) { m1[r][j] = -FLT_MAX; m2[r][j] = -FLT_MAX; i1[r][j] = 0; }

    asm volatile("s_waitcnt vmcnt(0)" ::: "memory");
    __syncthreads();

    for (int ch = 0; ch < NCH; ++ch) {
        const int cur = ch & 1;
        if (ch + 1 < NCH) stage(cur ^ 1, ch + 1);     // prefetch next chunk (async)
        const char* buf = &Wbuf[cur][0];

        #pragma unroll
        for (int t = 0; t < 2; ++t) {
            const int code_l = t * 16 + lm;
            const int c = ch * CHUNK + code_l;
            const float cinit = wn2_s[c];             // -0.5*||w||^2
            half8 bh[4], bl[4];
            #pragma unroll
            for (int ks = 0; ks < 4; ++ks) {
                const int off = code_l * 256 + ((((ks << 2) + lg) ^ (code_l & 7)) << 4);
                bh[ks] = *(const half8*)(buf + off);
                bl[ks] = *(const half8*)(buf + 8192 + off);
            }
            f32x4 acc[4];
            #pragma unroll
            for (int r = 0; r < 4; ++r) acc[r] = (f32x4){cinit, cinit, cinit, cinit};
            #pragma unroll
            for (int ks = 0; ks < 4; ++ks) {
                #pragma unroll
                for (int r = 0; r < 4; ++r) {
                    acc[r] = __builtin_amdgcn_mfma_f32_16x16x32_f16(ah[r][ks], bh[ks], acc[r], 0, 0, 0);
                    acc[r] = __builtin_amdgcn_mfma_f32_16x16x32_f16(ah[r][ks], bl[ks], acc[r], 0, 0, 0);
                }
            }
            #pragma unroll
            for (int r = 0; r < 4; ++r) {
                #pragma unroll
                for (int j = 0; j < 4; ++j) {
                    const float a = acc[r][j];
                    m2[r][j] = __builtin_amdgcn_fmed3f(a, m1[r][j], m2[r][j]);
                    const bool gt = a > m1[r][j];
                    m1[r][j] = fmaxf(m1[r][j], a);
                    i1[r][j] = gt ? c : i1[r][j];
                }
            }
        }
        asm volatile("s_waitcnt vmcnt(0)" ::: "memory");  // next chunk landed
        __syncthreads();                                   // all waves done with buf
    }

    // ---- reduce (m1, idx, m2) across the 16 col-lanes ----
    #pragma unroll
    for (int sft = 1; sft < 16; sft <<= 1) {
        #pragma unroll
        for (int r = 0; r < 4; ++r) {
            #pragma unroll
            for (int j = 0; j < 4; ++j) {
                float o1 = __shfl_xor(m1[r][j], sft);
                float o2 = __shfl_xor(m2[r][j], sft);
                int   oi = __shfl_xor(i1[r][j], sft);
                if (o1 > m1[r][j] || (o1 == m1[r][j] && oi < i1[r][j])) {
                    m2[r][j] = fmaxf(m1[r][j], o2);
                    m1[r][j] = o1;
                    i1[r][j] = oi;
                } else {
                    m2[r][j] = fmaxf(m2[r][j], o1);
                }
            }
        }
    }

    float psum = 0.f;
    if (lm == 0) {
        #pragma unroll
        for (int r = 0; r < 4; ++r) {
            #pragma unroll
            for (int j = 0; j < 4; ++j) {
                const int row = w * RPW + r * 16 + lg * 4 + j;   // C row = lg*4 + reg
                sIdx[row]  = i1[r][j];
                sFlag[row] = (m1[r][j] - m2[r][j] < TAU_A) ? 1 : 0;
                // dist^2 = ||x||^2 - 2*a
                psum += xn_s[row] - 2.f * m1[r][j];
            }
        }
    }
    __syncthreads();

    // ---- fp64 exact refinement of near-tie rows (ballot-dispatched, rare) ----
    {
        const int rbase = w * RPW;
        unsigned long long fl = __ballot(sFlag[rbase + lane] != 0);
        while (fl) {
            const int rr = rbase + (__ffsll(fl) - 1);
            fl &= fl - 1;
            const float* xp = Z + (row0 + rr) * Dn;
            double best = 1e300; int bi = 0;
            for (int jj = 0; jj < 8; ++jj) {
                const int k = lane + 64 * jj;
                const float* wp = W + (size_t)k * Dn;
                double s = 0.0;
                for (int i = 0; i < Dn; ++i) {
                    double dx = (double)xp[i] - (double)wp[i];
                    s += dx * dx;
                }
                if (s < best) { best = s; bi = k; }
            }
            #pragma unroll
            for (int sft = 1; sft < 64; sft <<= 1) {
                double ob = __shfl_xor(best, sft);
                int    ok = __shfl_xor(bi, sft);
                if (ob < best || (ob == best && ok < bi)) { best = ob; bi = ok; }
            }
            if (lane == 0) sIdx[rr] = bi;
        }
    }
    __syncthreads();

    // ---- epilogue: z_q_st == W[ind] gather; indices; diff partial ----
    #pragma unroll
    for (int it = 0; it < 32; ++it) {
        int f4i = tid + it * 128;              // 0..4095
        int row = f4i >> 5, cq = f4i & 31;
        int ind = sIdx[row];
        float4 wv = ((const float4*)(W + (size_t)ind * Dn))[cq];
        ((float4*)(out + (row0 + row) * Dn))[cq] = wv;
    }
    out[IND_OFF + row0 + tid] = (float)sIdx[tid];   // 128 threads = RPB rows

    #pragma unroll
    for (int sft = 1; sft < 64; sft <<= 1) psum += __shfl_xor(psum, sft);
    if (lane == 0) wpart[w] = psum;
    __syncthreads();
    if (tid == 0) {
        double t = (double)wpart[0] + (double)wpart[1];
        atomicAdd(diffsum, t);
    }
}

__global__ void diff_kernel(const double* __restrict__ diffsum, float* __restrict__ out) {
    if (threadIdx.x == 0 && blockIdx.x == 0) {
        // KLD_SCALE * (COMMITMENT_COST + 1) * mean = 12.5 * mean
        out[DIFF_OFF] = (float)(12.5 * diffsum[0] / (double)ZQ_SIZE);
    }
}

extern "C" void kernel_launch(void* const* d_in, const int* in_sizes, int n_in,
                              void* d_out, int out_size, void* d_ws, size_t ws_size,
                              hipStream_t stream) {
    (void)in_sizes; (void)n_in; (void)out_size; (void)ws_size;
    const float* Z = (const float*)d_in[0];
    const float* W = (const float*)d_in[1];
    float* out = (float*)d_out;
    // ws layout: [0,8) diffsum double; [16,2064) wn2 f32[512]; [4096, +256KB) Wp
    double* diffsum = (double*)d_ws;
    float* wn2 = (float*)((char*)d_ws + 16);
    unsigned short* Wp = (unsigned short*)((char*)d_ws + 4096);

    hipMemsetAsync(d_ws, 0, 16, stream);
    wnorm_kernel<<<2, 256, 0, stream>>>(W, wn2);
    prep_kernel<<<32, 256, 0, stream>>>(W, Wp);
    vq_main<<<NBLK, 128, 0, stream>>>(Z, W, Wp, wn2, out, diffsum);
    diff_kernel<<<1, 64, 0, stream>>>(diffsum, out);
}

// Round 6
// 112.860 us; speedup vs baseline: 1.5393x; 1.5393x over previous
//
#include <hip/hip_runtime.h>
#include <float.h>

// Quantize: z [8,4096,512] f32, embed_w [512,128] f32, GROUPS=4
// flat = z.reshape(131072,128); dist to 512 codes; argmin; gather; MSE scalar.
// d_out (f32): z_q_st [16777216], diff [1], ind [131072] (as float).
//
// Single-pass design: fp16-hi codebook (128 KB) resident in LDS for the whole
// kernel (loaded once, ONE barrier), 16 waves x 32 rows per block, no in-loop
// synchronization. Scores a = x16.w16 - 0.5*||w||^2 via MFMA; rows whose
// top-2 margin < TAU_A are re-solved exactly in fp64 against fp32 W
// (block-distributed, coalesced) => exact argmin indices.

typedef _Float16 half8 __attribute__((ext_vector_type(8)));
typedef __attribute__((ext_vector_type(4))) float f32x4;

constexpr int Dn = 128;
constexpr int K  = 512;
constexpr long long Mrows = 131072;
constexpr int RPW   = 32;                    // rows per wave
constexpr int WAVES = 16;                    // waves per block (1024 threads)
constexpr int RPB   = RPW * WAVES;           // 512 rows per block
constexpr int NBLK  = (int)(Mrows / RPB);    // 256
constexpr float TAU_A = 0.05f;               // score-margin for fp64 re-solve (~20 sigma)

constexpr size_t ZQ_SIZE  = (size_t)Mrows * Dn;
constexpr size_t DIFF_OFF = ZQ_SIZE;
constexpr size_t IND_OFF  = ZQ_SIZE + 1;

__device__ inline void gload_lds16(const void* g, void* l) {
    __builtin_amdgcn_global_load_lds(
        (const __attribute__((address_space(1))) unsigned int*)g,
        (__attribute__((address_space(3))) unsigned int*)l,
        16, 0, 0);
}

__global__ void wnorm_kernel(const float* __restrict__ W, float* __restrict__ wn2) {
    int k = blockIdx.x * blockDim.x + threadIdx.x;
    if (k < K) {
        double s = 0.0;
        const float* w = W + (size_t)k * Dn;
        #pragma unroll 4
        for (int i = 0; i < Dn; ++i) { double v = (double)w[i]; s += v * v; }
        wn2[k] = (float)(-0.5 * s);
    }
}

// W -> fp16 (hi only), pre-swizzled granule order over the whole codebook.
// Granule index G = code*16 + gs holds dims (gs ^ (code&7))*8 .. +8 of `code`
// (8 halfs per 16 B granule), so a LINEAR global_load_lds DMA puts each
// granule where the swizzled ds_read expects it.
__global__ void prep_kernel(const float* __restrict__ W, unsigned short* __restrict__ Wp) {
    int t = blockIdx.x * 256 + threadIdx.x;  // 0..8191 (512 codes * 16 granules)
    int code = t >> 4;
    int gs   = t & 15;
    int g    = gs ^ (code & 7);
    const float* src = W + (size_t)code * Dn + g * 8;
    ushort4 h[2];
    #pragma unroll
    for (int half = 0; half < 2; ++half) {
        float4 v = *(const float4*)(src + half * 4);
        float vv[4] = {v.x, v.y, v.z, v.w};
        unsigned short* hp = (unsigned short*)&h[half];
        #pragma unroll
        for (int e = 0; e < 4; ++e) {
            _Float16 hh = (_Float16)vv[e];
            hp[e] = __builtin_bit_cast(unsigned short, hh);
        }
    }
    size_t base = (size_t)t * 8;             // ushort units
    *(ushort4*)(Wp + base)     = h[0];
    *(ushort4*)(Wp + base + 4) = h[1];
}

__global__ __launch_bounds__(1024, 4) void vq_main(
        const float* __restrict__ Z, const float* __restrict__ W,
        const unsigned short* __restrict__ Wp, const float* __restrict__ wn2,
        float* __restrict__ out, double* __restrict__ diffsum) {
    __shared__ __align__(16) char Wlds[131072];   // full codebook, fp16 hi, swizzled
    __shared__ float wn2_s[K];
    __shared__ float xn_s[RPB];
    __shared__ int   sIdx[RPB];
    __shared__ int   flagList[RPB];
    __shared__ int   flagN;
    __shared__ float wpart[WAVES];

    const int tid  = threadIdx.x;
    const int w    = tid >> 6;
    const int lane = tid & 63;
    const int lm   = lane & 15;        // A row / B col within 16-tile
    const int lg   = lane >> 4;        // k-block (0..3)
    const size_t row0 = (size_t)blockIdx.x * RPB;

    if (tid == 0) flagN = 0;

    // ---- codebook DMA: 128 KB, issued once, linear dest (pre-swizzled src) ----
    {
        const char* gsrc = (const char*)Wp;
        #pragma unroll
        for (int it = 0; it < 8; ++it) {
            const int gbase = it * 1024 + w * 64;            // wave-uniform granule base
            gload_lds16(gsrc + (size_t)(gbase + lane) * 16, Wlds + (size_t)gbase * 16);
        }
    }
    if (tid < K) wn2_s[tid] = wn2[tid];

    // ---- X fragments (fp16) + exact row norms (overlaps the DMA) ----
    half8 ah[2][4];                     // [16-row tile][ks]
    #pragma unroll
    for (int r = 0; r < 2; ++r) {
        const size_t grow = row0 + (size_t)w * RPW + r * 16 + lm;
        float s2 = 0.f;
        #pragma unroll
        for (int ks = 0; ks < 4; ++ks) {
            const float* xp = Z + grow * Dn + ks * 32 + lg * 8;
            float4 x0 = *(const float4*)xp;
            float4 x1 = *(const float4*)(xp + 4);
            float xv[8] = {x0.x, x0.y, x0.z, x0.w, x1.x, x1.y, x1.z, x1.w};
            #pragma unroll
            for (int j = 0; j < 8; ++j) {
                ah[r][ks][j] = (_Float16)xv[j];
                s2 += xv[j] * xv[j];
            }
        }
        s2 += __shfl_xor(s2, 16);
        s2 += __shfl_xor(s2, 32);      // full ||x||^2 for row grow
        if (lg == 0) xn_s[w * RPW + r * 16 + lm] = s2;
    }

    // max-tracking of a = dot - 0.5*||w||^2  (argmin dist == argmax a)
    float m1[2][4], m2[2][4];
    int   i1[2][4];
    #pragma unroll
    for (int r = 0; r < 2; ++r)
        #pragma unroll
        for (int j = 0; j < 4; ++j) { m1[r][j] = -FLT_MAX; m2[r][j] = -FLT_MAX; i1[r][j] = 0; }

    asm volatile("s_waitcnt vmcnt(0)" ::: "memory");
    __syncthreads();                   // codebook resident; ONLY barrier before epilogue

    // ---- main loop: 32 B-tiles x (2 A-tiles x 4 k-steps), no syncs ----
    #pragma unroll 2
    for (int t = 0; t < 32; ++t) {
        const int code = t * 16 + lm;
        const float cinit = wn2_s[code];
        half8 bh[4];
        #pragma unroll
        for (int ks = 0; ks < 4; ++ks) {
            const int off = code * 256 + ((((ks << 2) + lg) ^ (code & 7)) << 4);
            bh[ks] = *(const half8*)(Wlds + off);
        }
        f32x4 acc[2];
        #pragma unroll
        for (int r = 0; r < 2; ++r) acc[r] = (f32x4){cinit, cinit, cinit, cinit};
        #pragma unroll
        for (int ks = 0; ks < 4; ++ks) {
            #pragma unroll
            for (int r = 0; r < 2; ++r)
                acc[r] = __builtin_amdgcn_mfma_f32_16x16x32_f16(ah[r][ks], bh[ks], acc[r], 0, 0, 0);
        }
        #pragma unroll
        for (int r = 0; r < 2; ++r) {
            #pragma unroll
            for (int j = 0; j < 4; ++j) {
                const float a = acc[r][j];
                m2[r][j] = __builtin_amdgcn_fmed3f(a, m1[r][j], m2[r][j]);
                const bool gt = a > m1[r][j];
                m1[r][j] = fmaxf(m1[r][j], a);
                i1[r][j] = gt ? code : i1[r][j];
            }
        }
    }

    // ---- reduce (m1, idx, m2) across the 16 col-lanes ----
    #pragma unroll
    for (int sft = 1; sft < 16; sft <<= 1) {
        #pragma unroll
        for (int r = 0; r < 2; ++r) {
            #pragma unroll
            for (int j = 0; j < 4; ++j) {
                float o1 = __shfl_xor(m1[r][j], sft);
                float o2 = __shfl_xor(m2[r][j], sft);
                int   oi = __shfl_xor(i1[r][j], sft);
                if (o1 > m1[r][j] || (o1 == m1[r][j] && oi < i1[r][j])) {
                    m2[r][j] = fmaxf(m1[r][j], o2);
                    m1[r][j] = o1;
                    i1[r][j] = oi;
                } else {
                    m2[r][j] = fmaxf(m2[r][j], o1);
                }
            }
        }
    }

    float psum = 0.f;
    if (lm == 0) {
        #pragma unroll
        for (int r = 0; r < 2; ++r) {
            #pragma unroll
            for (int j = 0; j < 4; ++j) {
                const int row = w * RPW + r * 16 + lg * 4 + j;   // C row = lg*4 + reg
                sIdx[row] = i1[r][j];
                psum += xn_s[row] - 2.f * m1[r][j];              // dist^2 = ||x||^2 - 2a
                if (m1[r][j] - m2[r][j] < TAU_A) {
                    int pos = atomicAdd(&flagN, 1);
                    flagList[pos] = row;
                }
            }
        }
    }
    __syncthreads();

    // ---- fp64 exact refinement, block-distributed, coalesced ----
    {
        const int nflag = flagN;
        const int cg    = lane >> 3;           // code subgroup 0..7
        const int dbase = (lane & 7) * 16;     // 16-dim slice per lane
        for (int fi = w; fi < nflag; fi += WAVES) {
            const int rr = flagList[fi];
            const float* xp = Z + (row0 + rr) * Dn + dbase;
            double xd[16];
            #pragma unroll
            for (int q = 0; q < 16; q += 4) {
                float4 v = *(const float4*)(xp + q);
                xd[q] = v.x; xd[q+1] = v.y; xd[q+2] = v.z; xd[q+3] = v.w;
            }
            double best = 1e300; int bi = 0;
            for (int cb = 0; cb < 64; ++cb) {
                const int c = cb * 8 + cg;
                const float* wp = W + (size_t)c * Dn + dbase;
                double s = 0.0;
                #pragma unroll
                for (int q = 0; q < 16; q += 4) {
                    float4 wv = *(const float4*)(wp + q);
                    double d0 = xd[q]   - (double)wv.x;
                    double d1 = xd[q+1] - (double)wv.y;
                    double d2 = xd[q+2] - (double)wv.z;
                    double d3 = xd[q+3] - (double)wv.w;
                    s += d0 * d0 + d1 * d1 + d2 * d2 + d3 * d3;
                }
                s += __shfl_xor(s, 1);
                s += __shfl_xor(s, 2);
                s += __shfl_xor(s, 4);         // all 8 lanes of group hold s(c)
                if (s < best) { best = s; bi = c; }   // ascending c => min-idx tiebreak
            }
            #pragma unroll
            for (int sft = 8; sft < 64; sft <<= 1) {
                double ob = __shfl_xor(best, sft);
                int    ok = __shfl_xor(bi, sft);
                if (ob < best || (ob == best && ok < bi)) { best = ob; bi = ok; }
            }
            if (lane == 0) sIdx[rr] = bi;
        }
    }
    __syncthreads();

    // ---- epilogue: z_q_st == W[ind] gather; indices; diff partial ----
    #pragma unroll
    for (int it = 0; it < 16; ++it) {
        int f4i = tid + it * 1024;             // 0..16383
        int row = f4i >> 5, cq = f4i & 31;
        int ind = sIdx[row];
        float4 wv = ((const float4*)(W + (size_t)ind * Dn))[cq];
        ((float4*)(out + (row0 + row) * Dn))[cq] = wv;
    }
    if (tid < RPB) out[IND_OFF + row0 + tid] = (float)sIdx[tid];

    #pragma unroll
    for (int sft = 1; sft < 64; sft <<= 1) psum += __shfl_xor(psum, sft);
    if (lane == 0) wpart[w] = psum;
    __syncthreads();
    if (tid == 0) {
        double t = 0.0;
        #pragma unroll
        for (int i = 0; i < WAVES; ++i) t += (double)wpart[i];
        atomicAdd(diffsum, t);
    }
}

__global__ void diff_kernel(const double* __restrict__ diffsum, float* __restrict__ out) {
    if (threadIdx.x == 0 && blockIdx.x == 0) {
        // KLD_SCALE * (COMMITMENT_COST + 1) * mean = 12.5 * mean
        out[DIFF_OFF] = (float)(12.5 * diffsum[0] / (double)ZQ_SIZE);
    }
}

extern "C" void kernel_launch(void* const* d_in, const int* in_sizes, int n_in,
                              void* d_out, int out_size, void* d_ws, size_t ws_size,
                              hipStream_t stream) {
    (void)in_sizes; (void)n_in; (void)out_size; (void)ws_size;
    const float* Z = (const float*)d_in[0];
    const float* W = (const float*)d_in[1];
    float* out = (float*)d_out;
    // ws layout: [0,8) diffsum double; [16,2064) wn2 f32[512]; [4096, +128KB) Wp
    double* diffsum = (double*)d_ws;
    float* wn2 = (float*)((char*)d_ws + 16);
    unsigned short* Wp = (unsigned short*)((char*)d_ws + 4096);

    hipMemsetAsync(d_ws, 0, 16, stream);
    wnorm_kernel<<<2, 256, 0, stream>>>(W, wn2);
    prep_kernel<<<32, 256, 0, stream>>>(W, Wp);
    vq_main<<<NBLK, 1024, 0, stream>>>(Z, W, Wp, wn2, out, diffsum);
    diff_kernel<<<1, 64, 0, stream>>>(diffsum, out);
}